// Round 7
// baseline (221.214 us; speedup 1.0000x reference)
//
#include <hip/hip_runtime.h>
#include <math.h>

constexpr int KK = 2;
constexpr int HH = 4;
constexpr int NN = 4096;
constexpr int DD = 64;
constexpr int OO = 64;
constexpr int NU = 4000;
constexpr int CC = 2;
constexpr int JSPLIT = 16;
constexpr int JCHUNK = NN / JSPLIT;  // 256
constexpr float LOG2E = 1.44269504088896340736f;

typedef float vf4 __attribute__((ext_vector_type(4)));
typedef float vf2 __attribute__((ext_vector_type(2)));

__device__ __forceinline__ float fexp2(float x) {
#if __has_builtin(__builtin_amdgcn_exp2f)
  return __builtin_amdgcn_exp2f(x);
#else
  return exp2f(x);
#endif
}
__device__ __forceinline__ float frcp(float x) {
#if __has_builtin(__builtin_amdgcn_rcpf)
  return __builtin_amdgcn_rcpf(x);
#else
  return 1.0f / x;
#endif
}
__device__ __forceinline__ float ftanh(float x) {
  float e = fexp2(x * (2.0f * LOG2E));
  return 1.0f - 2.0f * frcp(e + 1.0f);
}

// ---------------------------------------------------------------------------
// Phase 1: per (k,h): hp = h @ w (4096x64 @ 64x64); per node i (PAIRED layout):
//   srcAA[kh][i] = {2^src', 2^(0.2 src')}   (src' = (tanh(hp_i).a_src)*log2e)
//   bb5  [kh][j] = {2^dst', 2^(0.2 dst')}
//   gg   [kh][j] = {hp_j.fc_w0, hp_j.fc_w1}
// Factorized leaky-softmax: exp2(max(s,0.2s)) = max(A*B, A5*B5).
// grid (64, K*H), block 256. Thread = 4 rows x 4 o tile; LDS transpose epi.
// ---------------------------------------------------------------------------
__global__ __launch_bounds__(256) void gat_phase1(
    const float* __restrict__ hsrc, const float* __restrict__ w,
    const float* __restrict__ a_src, const float* __restrict__ a_dst,
    const float* __restrict__ fc_w,
    float* __restrict__ srcAA, float* __restrict__ bb5,
    float* __restrict__ gg) {
  const int kh = blockIdx.y;  // 0..7
  const int k = kh >> 2;
  const int i0 = blockIdx.x * 64;
  const int tid = threadIdx.x;

  __shared__ float h_s[DD][68];
  __shared__ float w_s[DD][OO];
  __shared__ float part[4][64][17];  // [val][row][og], padded

  {
    const vf4* wp = (const vf4*)(w + (size_t)kh * DD * OO);
    vf4* ws4 = (vf4*)w_s;
    for (int t = tid; t < DD * OO / 4; t += 256) ws4[t] = wp[t];
  }
  for (int t = tid; t < 1024; t += 256) {
    const int row = t >> 4;
    const int f4 = (t & 15) * 4;
    vf4 v = *(const vf4*)(hsrc + (size_t)(i0 + row) * DD + f4);
    h_s[f4 + 0][row] = v.x;
    h_s[f4 + 1][row] = v.y;
    h_s[f4 + 2][row] = v.z;
    h_s[f4 + 3][row] = v.w;
  }
  __syncthreads();

  const int og = tid & 15;
  const int rg = tid >> 4;
  const int o0 = og * 4;
  const int r0 = rg * 4;

  float hp[4][4];
#pragma unroll
  for (int j = 0; j < 4; ++j)
#pragma unroll
    for (int u = 0; u < 4; ++u) hp[j][u] = 0.0f;

#pragma unroll 8
  for (int f = 0; f < DD; ++f) {
    vf4 hv = *(const vf4*)&h_s[f][r0];
    vf4 wv = *(const vf4*)&w_s[f][o0];
    hp[0][0] = fmaf(hv.x, wv.x, hp[0][0]);
    hp[0][1] = fmaf(hv.x, wv.y, hp[0][1]);
    hp[0][2] = fmaf(hv.x, wv.z, hp[0][2]);
    hp[0][3] = fmaf(hv.x, wv.w, hp[0][3]);
    hp[1][0] = fmaf(hv.y, wv.x, hp[1][0]);
    hp[1][1] = fmaf(hv.y, wv.y, hp[1][1]);
    hp[1][2] = fmaf(hv.y, wv.z, hp[1][2]);
    hp[1][3] = fmaf(hv.y, wv.w, hp[1][3]);
    hp[2][0] = fmaf(hv.z, wv.x, hp[2][0]);
    hp[2][1] = fmaf(hv.z, wv.y, hp[2][1]);
    hp[2][2] = fmaf(hv.z, wv.z, hp[2][2]);
    hp[2][3] = fmaf(hv.z, wv.w, hp[2][3]);
    hp[3][0] = fmaf(hv.w, wv.x, hp[3][0]);
    hp[3][1] = fmaf(hv.w, wv.y, hp[3][1]);
    hp[3][2] = fmaf(hv.w, wv.z, hp[3][2]);
    hp[3][3] = fmaf(hv.w, wv.w, hp[3][3]);
  }

  float as[4], ad[4], f0[4], f1[4];
#pragma unroll
  for (int u = 0; u < 4; ++u) {
    as[u] = a_src[kh * OO + o0 + u];
    ad[u] = a_dst[kh * OO + o0 + u];
    f0[u] = fc_w[0 * (KK * OO) + k * OO + o0 + u];
    f1[u] = fc_w[1 * (KK * OO) + k * OO + o0 + u];
  }

#pragma unroll
  for (int j = 0; j < 4; ++j) {
    float sp = 0.0f, dp = 0.0f, g0 = 0.0f, g1 = 0.0f;
#pragma unroll
    for (int u = 0; u < 4; ++u) {
      float v = hp[j][u];
      float t = ftanh(v);
      sp = fmaf(t, as[u], sp);
      dp = fmaf(t, ad[u], dp);
      g0 = fmaf(v, f0[u], g0);
      g1 = fmaf(v, f1[u], g1);
    }
    part[0][r0 + j][og] = sp;
    part[1][r0 + j][og] = dp;
    part[2][r0 + j][og] = g0;
    part[3][r0 + j][og] = g1;
  }
  __syncthreads();

  {  // wave = val plane (uniform branch), lane = row j2; sum 16 og-partials
    const int val = tid >> 6;
    const int j2 = tid & 63;
    const float* pr = &part[val][j2][0];
    vf4 s0 = *(const vf4*)(pr + 0);
    vf4 s1 = *(const vf4*)(pr + 4);
    vf4 s2 = *(const vf4*)(pr + 8);
    vf4 s3 = *(const vf4*)(pr + 12);
    vf4 t4 = s0 + s1 + s2 + s3;
    float sum = t4.x + t4.y + t4.z + t4.w;
    const size_t idx = (size_t)kh * NN + i0 + j2;
    if (val == 0) {
      float sp = sum * LOG2E;
      vf2 v = {fexp2(sp), fexp2(0.2f * sp)};
      *(vf2*)(srcAA + idx * 2) = v;
    } else if (val == 1) {
      float dp = sum * LOG2E;
      vf2 v = {fexp2(dp), fexp2(0.2f * dp)};
      *(vf2*)(bb5 + idx * 2) = v;
    } else {
      gg[idx * 2 + (val - 2)] = sum;
    }
  }
}

// ---------------------------------------------------------------------------
// Phase 2: R6 structure with exactly ONE change: each thread serves TWO rows
// (r0+row, r0+16+row) from the same LDS reads -> DS-pipe cycles per row halve.
// grid (NU/32, K*JSPLIT) = (125, 32), block 256 = 4 waves.
// LDS: paired (B,B5)/(g0,g1) planes 16 KB + 6 KB sred. Paired layout, pk
// inner loop, upfront plain adjacency prefetch — all identical to R6.
//   e = max(A*B, A5*B5)  [== exp2(leaky(s)), exact identity]
//   pa = adj*e; l += pa; a_c += pa*g_c
// ---------------------------------------------------------------------------
__global__ __launch_bounds__(256) void gat_phase2(
    const float* __restrict__ adj, const float* __restrict__ srcAA,
    const float* __restrict__ bb5, const float* __restrict__ gg,
    float* __restrict__ P) {
  const int k = blockIdx.y >> 4;
  const int chunk = blockIdx.y & 15;
  const int r0 = blockIdx.x * 32;
  const int tid = threadIdx.x;
  const int wave = tid >> 6;
  const int lane = tid & 63;
  const int row = lane & 15;
  const int jsub = lane >> 4;
  const int i0r = r0 + row;
  const int i1r = r0 + 16 + row;
  const int j0 = chunk * JCHUNK;

  __shared__ float lds_bb[HH][JCHUNK * 2];
  __shared__ float lds_gg[HH][JCHUNK * 2];

  // stage both pair-planes: 2 arrays x 4 h x 512 floats = 1024 vf4
#pragma unroll
  for (int step = 0; step < 4; ++step) {
    const int idx = step * 256 + tid;
    const int sel = idx >> 9;
    const int h = (idx >> 7) & 3;
    const int pos = (idx & 127) * 4;
    const float* src =
        (sel ? gg : bb5) + ((size_t)(k * HH + h) * NN + j0) * 2 + pos;
    vf4 v = *(const vf4*)src;
    if (sel)
      *(vf4*)&lds_gg[h][pos] = v;
    else
      *(vf4*)&lds_bb[h][pos] = v;
  }

  vf2 AA0[4], AA1[4];
#pragma unroll
  for (int h = 0; h < 4; ++h) {
    AA0[h] = *(const vf2*)(srcAA + ((size_t)(k * HH + h) * NN + i0r) * 2);
    AA1[h] = *(const vf2*)(srcAA + ((size_t)(k * HH + h) * NN + i1r) * 2);
  }

  float l0[4], a00[4], a10[4], l1[4], a01[4], a11[4];
#pragma unroll
  for (int h = 0; h < 4; ++h) {
    l0[h] = 0.0f; a00[h] = 0.0f; a10[h] = 0.0f;
    l1[h] = 0.0f; a01[h] = 0.0f; a11[h] = 0.0f;
  }

  __syncthreads();

  // 16 tiles of 16 j; wave handles t = wave + s*4, s=0..3, all prefetched.
  const size_t abase = (size_t)k * NN * NN + j0 + jsub * 4;
  const float* ar0 = adj + abase + (size_t)i0r * NN;
  const float* ar1 = adj + abase + (size_t)i1r * NN;
  vf4 aj0[4], aj1[4];
#pragma unroll
  for (int q = 0; q < 4; ++q) {
    aj0[q] = *(const vf4*)(ar0 + (wave + q * 4) * 16);
    aj1[q] = *(const vf4*)(ar1 + (wave + q * 4) * 16);
  }

#pragma unroll
  for (int s = 0; s < 4; ++s) {
    const int t = wave + s * 4;
    const vf4 av0 = aj0[s];
    const vf4 av1 = aj1[s];
    const int jl = (t * 16 + jsub * 4) * 2;
#pragma unroll
    for (int h = 0; h < 4; ++h) {
      vf4 b01 = *(const vf4*)&lds_bb[h][jl];
      vf4 b23 = *(const vf4*)&lds_bb[h][jl + 4];
      vf4 g01 = *(const vf4*)&lds_gg[h][jl];
      vf4 g23 = *(const vf4*)&lds_gg[h][jl + 4];
      vf2 bp[4] = {{b01.x, b01.y}, {b01.z, b01.w}, {b23.x, b23.y}, {b23.z, b23.w}};
      vf2 gp[4] = {{g01.x, g01.y}, {g01.z, g01.w}, {g23.x, g23.y}, {g23.z, g23.w}};
#pragma unroll
      for (int jj = 0; jj < 4; ++jj) {
        vf2 P0 = AA0[h] * bp[jj];          // v_pk_mul_f32: {A*B, A5*B5}
        float e0 = fmaxf(P0.x, P0.y);      // = exp2(leaky(s)), exact
        float pa0 = e0 * av0[jj];
        l0[h] += pa0;
        a00[h] = fmaf(pa0, gp[jj].x, a00[h]);
        a10[h] = fmaf(pa0, gp[jj].y, a10[h]);
        vf2 P1 = AA1[h] * bp[jj];
        float e1 = fmaxf(P1.x, P1.y);
        float pa1 = e1 * av1[jj];
        l1[h] += pa1;
        a01[h] = fmaf(pa1, gp[jj].x, a01[h]);
        a11[h] = fmaf(pa1, gp[jj].y, a11[h]);
      }
    }
  }

  // butterfly over jsub (lane bits 4,5) for both rows
#pragma unroll
  for (int h = 0; h < 4; ++h) {
    l0[h] += __shfl_xor(l0[h], 16, 64);
    l0[h] += __shfl_xor(l0[h], 32, 64);
    a00[h] += __shfl_xor(a00[h], 16, 64);
    a00[h] += __shfl_xor(a00[h], 32, 64);
    a10[h] += __shfl_xor(a10[h], 16, 64);
    a10[h] += __shfl_xor(a10[h], 32, 64);
    l1[h] += __shfl_xor(l1[h], 16, 64);
    l1[h] += __shfl_xor(l1[h], 32, 64);
    a01[h] += __shfl_xor(a01[h], 16, 64);
    a01[h] += __shfl_xor(a01[h], 32, 64);
    a11[h] += __shfl_xor(a11[h], 16, 64);
    a11[h] += __shfl_xor(a11[h], 32, 64);
  }

  // cross-wave combine: sred[wave][v][rr], rr = row + 16*half.
  // lanes 0-15 write row-set 0, lanes 16-31 write row-set 1 (cndmask select).
  __shared__ float sred[4][12][32];
  if (lane < 32) {
    const int half = lane >> 4;
    const int rr = row + 16 * half;
#pragma unroll
    for (int h = 0; h < 4; ++h) {
      sred[wave][h * 3 + 0][rr] = half ? l1[h] : l0[h];
      sred[wave][h * 3 + 1][rr] = half ? a01[h] : a00[h];
      sred[wave][h * 3 + 2][rr] = half ? a11[h] : a10[h];
    }
  }
  __syncthreads();
  if (tid < 192) {
    const int v = tid >> 4;  // 0..11 = h*3+c
    const int h = v / 3, c = v % 3;
    const size_t pbase =
        ((((size_t)(k * JSPLIT + chunk) * HH + h) * 3 + c)) * NU + r0;
#pragma unroll
    for (int half = 0; half < 2; ++half) {
      const int rr = (tid & 15) + 16 * half;
      float sum =
          sred[0][v][rr] + sred[1][v][rr] + sred[2][v][rr] + sred[3][v][rr];
      P[pbase + rr] = sum;
    }
  }
}

// ---------------------------------------------------------------------------
// Phase 3: combine chunk partials, divide, mean heads, sum kinds, +bias,
// log_softmax over C=2. g = tid>>5 (wave-half-uniform plane) -> 128B
// coalesced P reads; LDS combine across the 8 (k,h) groups.
// ---------------------------------------------------------------------------
__global__ __launch_bounds__(256) void gat_phase3(
    const float* __restrict__ P, const float* __restrict__ fc_b,
    float* __restrict__ out) {
  const int tid = threadIdx.x;
  const int il = tid & 31;
  const int g = tid >> 5;  // 0..7 = (k,h), uniform per 32-lane half
  const int i = blockIdx.x * 32 + il;  // 125*32 == NU exactly
  const int k = g >> 2, h = g & 3;

  float ls = 0.0f, a0 = 0.0f, a1 = 0.0f;
#pragma unroll
  for (int ch = 0; ch < JSPLIT; ++ch) {
    size_t b = (((size_t)(k * JSPLIT + ch) * HH + h) * 3) * NU + i;
    ls += P[b];
    a0 += P[b + NU];
    a1 += P[b + 2 * (size_t)NU];
  }
  float inv = 1.0f / ls;
  float p0 = 0.25f * a0 * inv;
  float p1 = 0.25f * a1 * inv;

  __shared__ float s0[8][33], s1[8][33];
  s0[g][il] = p0;
  s1[g][il] = p1;
  __syncthreads();

  if (tid < 32) {
    float l0 = fc_b[0], l1 = fc_b[1];
#pragma unroll
    for (int g2 = 0; g2 < 8; ++g2) {
      l0 += s0[g2][tid];
      l1 += s1[g2][tid];
    }
    const int io = blockIdx.x * 32 + tid;
    float m = fmaxf(l0, l1);
    float lse = m + logf(expf(l0 - m) + expf(l1 - m));
    vf2 r = {l0 - lse, l1 - lse};
    *(vf2*)(out + (size_t)io * CC) = r;
  }
}

extern "C" void kernel_launch(void* const* d_in, const int* in_sizes, int n_in,
                              void* d_out, int out_size, void* d_ws, size_t ws_size,
                              hipStream_t stream) {
  const float* hsrc  = (const float*)d_in[0];  // (1,4096,64)
  const float* hadj  = (const float*)d_in[1];  // (2,1,4096,4096)
  const float* w     = (const float*)d_in[2];  // (2,4,64,64)
  const float* a_src = (const float*)d_in[3];  // (2,4,64,1)
  const float* a_dst = (const float*)d_in[4];  // (2,4,64,1)
  const float* fc_w  = (const float*)d_in[5];  // (2,128)
  const float* fc_b  = (const float*)d_in[6];  // (2,)
  float* out = (float*)d_out;                  // (1,4000,2) fp32

  char* ws = (char*)d_ws;
  float* srcAA = (float*)(ws + 0);        // K*H*N float2  (256 KB)
  float* bb5   = (float*)(ws + 262144);   // K*H*N float2  (256 KB)
  float* gg    = (float*)(ws + 524288);   // K*H*N float2  (256 KB)
  float* P     = (float*)(ws + 786432);   // K*JSPLIT*H*3*NU floats (~6.1 MB)

  dim3 g1(NN / 64, KK * HH);
  gat_phase1<<<g1, 256, 0, stream>>>(hsrc, w, a_src, a_dst, fc_w,
                                     srcAA, bb5, gg);
  dim3 g2(NU / 32, KK * JSPLIT);
  gat_phase2<<<g2, 256, 0, stream>>>(hadj, srcAA, bb5, gg, P);
  gat_phase3<<<NU / 32, 256, 0, stream>>>(P, fc_b, out);
}

// Round 8
// 212.992 us; speedup vs baseline: 1.0386x; 1.0386x over previous
//
#include <hip/hip_runtime.h>
#include <math.h>

constexpr int KK = 2;
constexpr int HH = 4;
constexpr int NN = 4096;
constexpr int DD = 64;
constexpr int OO = 64;
constexpr int NU = 4000;
constexpr int CC = 2;
constexpr int JSPLIT = 16;
constexpr int JCHUNK = NN / JSPLIT;  // 256
constexpr float LOG2E = 1.44269504088896340736f;

typedef float vf4 __attribute__((ext_vector_type(4)));
typedef float vf2 __attribute__((ext_vector_type(2)));

__device__ __forceinline__ float fexp2(float x) {
#if __has_builtin(__builtin_amdgcn_exp2f)
  return __builtin_amdgcn_exp2f(x);
#else
  return exp2f(x);
#endif
}
__device__ __forceinline__ float frcp(float x) {
#if __has_builtin(__builtin_amdgcn_rcpf)
  return __builtin_amdgcn_rcpf(x);
#else
  return 1.0f / x;
#endif
}
__device__ __forceinline__ float ftanh(float x) {
  float e = fexp2(x * (2.0f * LOG2E));
  return 1.0f - 2.0f * frcp(e + 1.0f);
}

// ---------------------------------------------------------------------------
// Phase 1: per (k,h): hp = h @ w (4096x64 @ 64x64); per node i (PAIRED layout):
//   srcAA[kh][i] = {2^src', 2^(0.2 src')}   (src' = (tanh(hp_i).a_src)*log2e)
//   bb5  [kh][j] = {2^dst', 2^(0.2 dst')}
//   gg   [kh][j] = {hp_j.fc_w0, hp_j.fc_w1}
// Factorized leaky-softmax: exp2(max(s,0.2s)) = max(A*B, A5*B5).
// grid (64, K*H), block 256. Thread = 4 rows x 4 o tile; LDS transpose epi.
// ---------------------------------------------------------------------------
__global__ __launch_bounds__(256) void gat_phase1(
    const float* __restrict__ hsrc, const float* __restrict__ w,
    const float* __restrict__ a_src, const float* __restrict__ a_dst,
    const float* __restrict__ fc_w,
    float* __restrict__ srcAA, float* __restrict__ bb5,
    float* __restrict__ gg) {
  const int kh = blockIdx.y;  // 0..7
  const int k = kh >> 2;
  const int i0 = blockIdx.x * 64;
  const int tid = threadIdx.x;

  __shared__ float h_s[DD][68];
  __shared__ float w_s[DD][OO];
  __shared__ float part[4][64][17];  // [val][row][og], padded

  {
    const vf4* wp = (const vf4*)(w + (size_t)kh * DD * OO);
    vf4* ws4 = (vf4*)w_s;
    for (int t = tid; t < DD * OO / 4; t += 256) ws4[t] = wp[t];
  }
  for (int t = tid; t < 1024; t += 256) {
    const int row = t >> 4;
    const int f4 = (t & 15) * 4;
    vf4 v = *(const vf4*)(hsrc + (size_t)(i0 + row) * DD + f4);
    h_s[f4 + 0][row] = v.x;
    h_s[f4 + 1][row] = v.y;
    h_s[f4 + 2][row] = v.z;
    h_s[f4 + 3][row] = v.w;
  }
  __syncthreads();

  const int og = tid & 15;
  const int rg = tid >> 4;
  const int o0 = og * 4;
  const int r0 = rg * 4;

  float hp[4][4];
#pragma unroll
  for (int j = 0; j < 4; ++j)
#pragma unroll
    for (int u = 0; u < 4; ++u) hp[j][u] = 0.0f;

#pragma unroll 8
  for (int f = 0; f < DD; ++f) {
    vf4 hv = *(const vf4*)&h_s[f][r0];
    vf4 wv = *(const vf4*)&w_s[f][o0];
    hp[0][0] = fmaf(hv.x, wv.x, hp[0][0]);
    hp[0][1] = fmaf(hv.x, wv.y, hp[0][1]);
    hp[0][2] = fmaf(hv.x, wv.z, hp[0][2]);
    hp[0][3] = fmaf(hv.x, wv.w, hp[0][3]);
    hp[1][0] = fmaf(hv.y, wv.x, hp[1][0]);
    hp[1][1] = fmaf(hv.y, wv.y, hp[1][1]);
    hp[1][2] = fmaf(hv.y, wv.z, hp[1][2]);
    hp[1][3] = fmaf(hv.y, wv.w, hp[1][3]);
    hp[2][0] = fmaf(hv.z, wv.x, hp[2][0]);
    hp[2][1] = fmaf(hv.z, wv.y, hp[2][1]);
    hp[2][2] = fmaf(hv.z, wv.z, hp[2][2]);
    hp[2][3] = fmaf(hv.z, wv.w, hp[2][3]);
    hp[3][0] = fmaf(hv.w, wv.x, hp[3][0]);
    hp[3][1] = fmaf(hv.w, wv.y, hp[3][1]);
    hp[3][2] = fmaf(hv.w, wv.z, hp[3][2]);
    hp[3][3] = fmaf(hv.w, wv.w, hp[3][3]);
  }

  float as[4], ad[4], f0[4], f1[4];
#pragma unroll
  for (int u = 0; u < 4; ++u) {
    as[u] = a_src[kh * OO + o0 + u];
    ad[u] = a_dst[kh * OO + o0 + u];
    f0[u] = fc_w[0 * (KK * OO) + k * OO + o0 + u];
    f1[u] = fc_w[1 * (KK * OO) + k * OO + o0 + u];
  }

#pragma unroll
  for (int j = 0; j < 4; ++j) {
    float sp = 0.0f, dp = 0.0f, g0 = 0.0f, g1 = 0.0f;
#pragma unroll
    for (int u = 0; u < 4; ++u) {
      float v = hp[j][u];
      float t = ftanh(v);
      sp = fmaf(t, as[u], sp);
      dp = fmaf(t, ad[u], dp);
      g0 = fmaf(v, f0[u], g0);
      g1 = fmaf(v, f1[u], g1);
    }
    part[0][r0 + j][og] = sp;
    part[1][r0 + j][og] = dp;
    part[2][r0 + j][og] = g0;
    part[3][r0 + j][og] = g1;
  }
  __syncthreads();

  {  // wave = val plane (uniform branch), lane = row j2; sum 16 og-partials
    const int val = tid >> 6;
    const int j2 = tid & 63;
    const float* pr = &part[val][j2][0];
    vf4 s0 = *(const vf4*)(pr + 0);
    vf4 s1 = *(const vf4*)(pr + 4);
    vf4 s2 = *(const vf4*)(pr + 8);
    vf4 s3 = *(const vf4*)(pr + 12);
    vf4 t4 = s0 + s1 + s2 + s3;
    float sum = t4.x + t4.y + t4.z + t4.w;
    const size_t idx = (size_t)kh * NN + i0 + j2;
    if (val == 0) {
      float sp = sum * LOG2E;
      vf2 v = {fexp2(sp), fexp2(0.2f * sp)};
      *(vf2*)(srcAA + idx * 2) = v;
    } else if (val == 1) {
      float dp = sum * LOG2E;
      vf2 v = {fexp2(dp), fexp2(0.2f * dp)};
      *(vf2*)(bb5 + idx * 2) = v;
    } else {
      gg[idx * 2 + (val - 2)] = sum;
    }
  }
}

// ---------------------------------------------------------------------------
// Phase 2: R6 winner config (16 rows/block, 8000 blocks) with ONE micro-change:
// the adjacency prefetch is issued BEFORE __syncthreads so the ~900-cycle HBM
// latency overlaps the barrier wait (LLVM can't hoist loads across the fence).
// grid (NU/16, K*JSPLIT) = (250, 32), block 256 = 4 waves.
// LDS: paired (B,B5)/(g0,g1) planes 16 KB + 3 KB sred.
//   e = max(A*B, A5*B5)  [== exp2(leaky(s)), exact identity]
//   pa = adj*e; l += pa; a_c += pa*g_c
// Reduction: butterfly xor 16,32 + LDS combine across 4 waves.
// ---------------------------------------------------------------------------
__global__ __launch_bounds__(256) void gat_phase2(
    const float* __restrict__ adj, const float* __restrict__ srcAA,
    const float* __restrict__ bb5, const float* __restrict__ gg,
    float* __restrict__ P) {
  const int k = blockIdx.y >> 4;
  const int chunk = blockIdx.y & 15;
  const int r0 = blockIdx.x * 16;
  const int tid = threadIdx.x;
  const int wave = tid >> 6;
  const int lane = tid & 63;
  const int row = lane & 15;
  const int jsub = lane >> 4;
  const int i = r0 + row;
  const int j0 = chunk * JCHUNK;

  __shared__ float lds_bb[HH][JCHUNK * 2];
  __shared__ float lds_gg[HH][JCHUNK * 2];

  // adjacency prefetch: issue FIRST (longest latency; overlaps staging+barrier)
  const float* arow =
      adj + (size_t)k * NN * NN + (size_t)i * NN + j0 + jsub * 4;
  vf4 aj[4];
#pragma unroll
  for (int q = 0; q < 4; ++q)
    aj[q] = *(const vf4*)(arow + (wave + q * 4) * 16);

  // stage both pair-planes: 2 arrays x 4 h x 512 floats = 1024 vf4
#pragma unroll
  for (int step = 0; step < 4; ++step) {
    const int idx = step * 256 + tid;
    const int sel = idx >> 9;
    const int h = (idx >> 7) & 3;
    const int pos = (idx & 127) * 4;
    const float* src =
        (sel ? gg : bb5) + ((size_t)(k * HH + h) * NN + j0) * 2 + pos;
    vf4 v = *(const vf4*)src;
    if (sel)
      *(vf4*)&lds_gg[h][pos] = v;
    else
      *(vf4*)&lds_bb[h][pos] = v;
  }

  vf2 AA[4];
#pragma unroll
  for (int h = 0; h < 4; ++h)
    AA[h] = *(const vf2*)(srcAA + ((size_t)(k * HH + h) * NN + i) * 2);

  float l[4], a0[4], a1[4];
#pragma unroll
  for (int h = 0; h < 4; ++h) {
    l[h] = 0.0f;
    a0[h] = 0.0f;
    a1[h] = 0.0f;
  }

  __syncthreads();

  // 16 tiles of 16 j; wave handles t = wave + s*4, s=0..3, all prefetched.
#pragma unroll
  for (int s = 0; s < 4; ++s) {
    const int t = wave + s * 4;
    const vf4 av = aj[s];
    const int jl = (t * 16 + jsub * 4) * 2;
#pragma unroll
    for (int h = 0; h < 4; ++h) {
      vf4 b01 = *(const vf4*)&lds_bb[h][jl];
      vf4 b23 = *(const vf4*)&lds_bb[h][jl + 4];
      vf4 g01 = *(const vf4*)&lds_gg[h][jl];
      vf4 g23 = *(const vf4*)&lds_gg[h][jl + 4];
      vf2 bp[4] = {{b01.x, b01.y}, {b01.z, b01.w}, {b23.x, b23.y}, {b23.z, b23.w}};
      vf2 gp[4] = {{g01.x, g01.y}, {g01.z, g01.w}, {g23.x, g23.y}, {g23.z, g23.w}};
#pragma unroll
      for (int jj = 0; jj < 4; ++jj) {
        vf2 PP = AA[h] * bp[jj];           // v_pk_mul_f32: {A*B, A5*B5}
        float e = fmaxf(PP.x, PP.y);       // = exp2(leaky(s)), exact
        float pa = e * av[jj];
        l[h] += pa;
        a0[h] = fmaf(pa, gp[jj].x, a0[h]);
        a1[h] = fmaf(pa, gp[jj].y, a1[h]);
      }
    }
  }

  // butterfly over jsub (lane bits 4,5)
#pragma unroll
  for (int h = 0; h < 4; ++h) {
    l[h] += __shfl_xor(l[h], 16, 64);
    l[h] += __shfl_xor(l[h], 32, 64);
    a0[h] += __shfl_xor(a0[h], 16, 64);
    a0[h] += __shfl_xor(a0[h], 32, 64);
    a1[h] += __shfl_xor(a1[h], 16, 64);
    a1[h] += __shfl_xor(a1[h], 32, 64);
  }

  // cross-wave combine: sred[wave][v][row], v = h*3+c
  __shared__ float sred[4][12][16];
  if (lane < 16) {
#pragma unroll
    for (int h = 0; h < 4; ++h) {
      sred[wave][h * 3 + 0][row] = l[h];
      sred[wave][h * 3 + 1][row] = a0[h];
      sred[wave][h * 3 + 2][row] = a1[h];
    }
  }
  __syncthreads();
  if (tid < 192) {
    const int v = tid >> 4;  // 0..11 = h*3+c
    const int rr = tid & 15;
    float sum =
        sred[0][v][rr] + sred[1][v][rr] + sred[2][v][rr] + sred[3][v][rr];
    const int h = v / 3, c = v % 3;
    // P layout: [k][chunk][h][{l,a0,a1}][i]
    size_t base =
        ((((size_t)(k * JSPLIT + chunk) * HH + h) * 3 + c)) * NU + (r0 + rr);
    P[base] = sum;
  }
}

// ---------------------------------------------------------------------------
// Phase 3: combine chunk partials, divide, mean heads, sum kinds, +bias,
// log_softmax over C=2. g = tid>>5 (wave-half-uniform plane) -> 128B
// coalesced P reads; LDS combine across the 8 (k,h) groups.
// ---------------------------------------------------------------------------
__global__ __launch_bounds__(256) void gat_phase3(
    const float* __restrict__ P, const float* __restrict__ fc_b,
    float* __restrict__ out) {
  const int tid = threadIdx.x;
  const int il = tid & 31;
  const int g = tid >> 5;  // 0..7 = (k,h), uniform per 32-lane half
  const int i = blockIdx.x * 32 + il;  // 125*32 == NU exactly
  const int k = g >> 2, h = g & 3;

  float ls = 0.0f, a0 = 0.0f, a1 = 0.0f;
#pragma unroll
  for (int ch = 0; ch < JSPLIT; ++ch) {
    size_t b = (((size_t)(k * JSPLIT + ch) * HH + h) * 3) * NU + i;
    ls += P[b];
    a0 += P[b + NU];
    a1 += P[b + 2 * (size_t)NU];
  }
  float inv = 1.0f / ls;
  float p0 = 0.25f * a0 * inv;
  float p1 = 0.25f * a1 * inv;

  __shared__ float s0[8][33], s1[8][33];
  s0[g][il] = p0;
  s1[g][il] = p1;
  __syncthreads();

  if (tid < 32) {
    float l0 = fc_b[0], l1 = fc_b[1];
#pragma unroll
    for (int g2 = 0; g2 < 8; ++g2) {
      l0 += s0[g2][tid];
      l1 += s1[g2][tid];
    }
    const int io = blockIdx.x * 32 + tid;
    float m = fmaxf(l0, l1);
    float lse = m + logf(expf(l0 - m) + expf(l1 - m));
    vf2 r = {l0 - lse, l1 - lse};
    *(vf2*)(out + (size_t)io * CC) = r;
  }
}

extern "C" void kernel_launch(void* const* d_in, const int* in_sizes, int n_in,
                              void* d_out, int out_size, void* d_ws, size_t ws_size,
                              hipStream_t stream) {
  const float* hsrc  = (const float*)d_in[0];  // (1,4096,64)
  const float* hadj  = (const float*)d_in[1];  // (2,1,4096,4096)
  const float* w     = (const float*)d_in[2];  // (2,4,64,64)
  const float* a_src = (const float*)d_in[3];  // (2,4,64,1)
  const float* a_dst = (const float*)d_in[4];  // (2,4,64,1)
  const float* fc_w  = (const float*)d_in[5];  // (2,128)
  const float* fc_b  = (const float*)d_in[6];  // (2,)
  float* out = (float*)d_out;                  // (1,4000,2) fp32

  char* ws = (char*)d_ws;
  float* srcAA = (float*)(ws + 0);        // K*H*N float2  (256 KB)
  float* bb5   = (float*)(ws + 262144);   // K*H*N float2  (256 KB)
  float* gg    = (float*)(ws + 524288);   // K*H*N float2  (256 KB)
  float* P     = (float*)(ws + 786432);   // K*JSPLIT*H*3*NU floats (~6.1 MB)

  dim3 g1(NN / 64, KK * HH);
  gat_phase1<<<g1, 256, 0, stream>>>(hsrc, w, a_src, a_dst, fc_w,
                                     srcAA, bb5, gg);
  dim3 g2(NU / 16, KK * JSPLIT);
  gat_phase2<<<g2, 256, 0, stream>>>(hadj, srcAA, bb5, gg, P);
  gat_phase3<<<NU / 32, 256, 0, stream>>>(P, fc_b, out);
}